// Round 6
// baseline (250.863 us; speedup 1.0000x reference)
//
#include <hip/hip_runtime.h>
#include <math.h>

#define BB 16
#define HH 512
#define WW 512
#define CC 4

typedef float f32x2 __attribute__((ext_vector_type(2)));
typedef float f32x4 __attribute__((ext_vector_type(4)));

// ---------------------------------------------------------------------------
// Kernel 1: column scan of logistic(defgrad.y) -> ys, plus planar
// logistic(defgrad.x) -> dgx (when workspace permits).  Unchanged from
// round 5 (streaming, LDS-tiled, nontemporal hints).
//   grid: BB * (WW/32) = 256 blocks; block: 1024 threads = 32 segs x 32 cols.
// ---------------------------------------------------------------------------
#define CS_COLS    32
#define CS_THREADS 1024
#define CS_SEGS    (CS_THREADS / CS_COLS)   // 32
#define CS_CHUNK   128
#define CS_SEGH    (CS_CHUNK / CS_SEGS)     // 4
#define CS_NCHUNK  (HH / CS_CHUNK)          // 4

__global__ __launch_bounds__(CS_THREADS)
void colscan_kernel(const f32x2* __restrict__ defgrad,
                    float* __restrict__ ys, int ys_stride,
                    float* __restrict__ dgx) {
    const int wt  = blockIdx.x % (WW / CS_COLS);
    const int b   = blockIdx.x / (WW / CS_COLS);
    const int tid = threadIdx.x;
    const int col = tid & (CS_COLS - 1);
    const int seg = tid >> 5;               // 0..31 (row base in load phase)

    __shared__ float lds[CS_CHUNK][CS_COLS + 1];
    __shared__ float part[CS_SEGS][CS_COLS];
    __shared__ float carry[2][CS_COLS];

    if (tid < CS_COLS) carry[0][tid] = 0.f;

    const size_t ibase = (size_t)b * HH * WW + wt * CS_COLS;  // + row*WW + col

    for (int c = 0; c < CS_NCHUNK; ++c) {
        // ---- load float2, logistic both channels, dgx out, .y into LDS
#pragma unroll
        for (int k = 0; k < 4; ++k) {
            const int r    = seg + k * 32;            // 0..127
            const int grow = c * CS_CHUNK + r;
            const size_t gi = ibase + (size_t)grow * WW + col;
            f32x2 v = __builtin_nontemporal_load(&defgrad[gi]);
            float lx = 2.0f / (1.0f + expf(-v.x));
            float ly = 2.0f / (1.0f + expf(-v.y));
            if (dgx) __builtin_nontemporal_store(lx, &dgx[gi]);
            lds[r][col] = ly;
        }
        __syncthreads();

        // ---- per-segment serial sums (kept in regs)
        float vals[CS_SEGH];
        float s = 0.f;
#pragma unroll
        for (int i = 0; i < CS_SEGH; ++i) {
            vals[i] = lds[seg * CS_SEGH + i][col];
            s += vals[i];
        }
        part[seg][col] = s;
        const float cold = carry[c & 1][col];
        __syncthreads();

        // ---- exclusive segment prefix + chunk total (broadcast reads)
        float run = cold, tot = cold;
#pragma unroll
        for (int j = 0; j < CS_SEGS; ++j) {
            float v = part[j][col];
            tot += v;
            if (j < seg) run += v;
        }
        if (seg == 0) carry[(c + 1) & 1][col] = tot;

        // ---- write inclusive scan values
        const size_t gidx0 =
            (size_t)(b * HH + c * CS_CHUNK + seg * CS_SEGH) * WW + wt * CS_COLS + col;
#pragma unroll
        for (int i = 0; i < CS_SEGH; ++i) {
            run += vals[i];
            __builtin_nontemporal_store(
                run, &ys[(gidx0 + (size_t)i * WW) * (size_t)ys_stride]);
        }
        __syncthreads();
    }
}

// ---------------------------------------------------------------------------
// Kernel 2: per-row fused — x_s row scan + residual affine + bilinear sample.
// v6: vmcnt purity + store coalescing.
//   * grid3 is staged in LDS (ds_write, lgkmcnt domain) so NO global store
//     precedes the gather asm -> its internal s_waitcnt vmcnt(0) drains ONLY
//     the 16 gathers (round 5 made every wave wait on write-acks of 12
//     fragmented 12B-stride NT stores -> dominant stall).
//   * After the blend, grid3 is dumped from LDS as contiguous float4 NT
//     stores (8x fewer store instrs, ~6x fewer transactions).
//   * dgx/ys loads lose the NT hint (let them hit L2/L3).
//   grid: BB*HH/4 = 2048 blocks; block: 512 threads (one per column).
// ---------------------------------------------------------------------------
#define RS_ROWS 4

__global__ __launch_bounds__(512, 4)
void rowscan_sample_kernel(const float4* __restrict__ im4,
                           const float2* __restrict__ defgrad,
                           const float*  __restrict__ affine,
                           const float*  __restrict__ ys, int ys_stride,
                           const float*  __restrict__ dgxp,
                           f32x4* __restrict__ out4,
                           float*  __restrict__ grid3) {
    // bijective XCD swizzle: 2048 % 8 == 0, consecutive logical ids per XCD
    const int nwg = BB * (HH / RS_ROWS);
    const int cpx = nwg / 8;
    const int l   = (blockIdx.x & 7) * cpx + (blockIdx.x >> 3);
    const int hb  = l % (HH / RS_ROWS);
    const int b   = l / (HH / RS_ROWS);
    const int h0  = hb * RS_ROWS;

    const int w    = threadIdx.x;          // 0..511 column
    const int lane = w & 63;
    const int wv   = w >> 6;               // 0..7

    const size_t imgbase  = (size_t)b * HH * WW;
    const size_t rowbase0 = imgbase + (size_t)h0 * WW + w;

    __shared__ __align__(16) float g_lds[RS_ROWS][WW * 3];  // staged grid3 rows
    __shared__ float wsum[8][RS_ROWS];

    // ---- early independent loads: dgx (planar or via logistic) and ys
    float dgxv[RS_ROWS], ysv[RS_ROWS];
    if (dgxp) {
#pragma unroll
        for (int r = 0; r < RS_ROWS; ++r) {
            const size_t pix = rowbase0 + (size_t)r * WW;
            dgxv[r] = dgxp[pix];
            ysv[r]  = ys[pix];
        }
    } else {
#pragma unroll
        for (int r = 0; r < RS_ROWS; ++r) {
            const size_t pix = rowbase0 + (size_t)r * WW;
            dgxv[r] = defgrad[pix].x;
            ysv[r]  = ys[pix * (size_t)ys_stride];
        }
#pragma unroll
        for (int r = 0; r < RS_ROWS; ++r)
            dgxv[r] = 2.0f / (1.0f + expf(-dgxv[r]));
    }

    // ---- 4 simultaneous inclusive block scans (wave scan + LDS combine)
    float x0 = dgxv[0], x1 = dgxv[1], x2 = dgxv[2], x3 = dgxv[3];
#pragma unroll
    for (int off = 1; off < 64; off <<= 1) {
        float n0 = __shfl_up(x0, off, 64);
        float n1 = __shfl_up(x1, off, 64);
        float n2 = __shfl_up(x2, off, 64);
        float n3 = __shfl_up(x3, off, 64);
        if (lane >= off) { x0 += n0; x1 += n1; x2 += n2; x3 += n3; }
    }
    if (lane == 63) {
        wsum[wv][0] = x0; wsum[wv][1] = x1; wsum[wv][2] = x2; wsum[wv][3] = x3;
    }
    __syncthreads();
    float p0 = 0.f, p1 = 0.f, p2 = 0.f, p3 = 0.f;
    for (int j = 0; j < wv; ++j) {
        p0 += wsum[j][0]; p1 += wsum[j][1]; p2 += wsum[j][2]; p3 += wsum[j][3];
    }
    const float xs[RS_ROWS] = { x0 + p0, x1 + p1, x2 + p2, x3 + p3 };

    // ---- residual affine (A = affine + I), uniform per block -> SGPRs
    const float* Ab = affine + b * 9;
    const float a00 = Ab[0] + 1.f, a01 = Ab[1], a02 = Ab[2];
    const float a10 = Ab[3], a11 = Ab[4] + 1.f, a12 = Ab[5];
    const float a20 = Ab[6], a21 = Ab[7], a22 = Ab[8] + 1.f;

    // ---- phase 1: addresses + weights; grid3 -> LDS (no global stores here!)
    int   bo [4 * RS_ROWS];                // byte voffsets (fit in 31 bits)
    float wgt[4 * RS_ROWS];
    const int base_b = (int)(imgbase * sizeof(float4));
#pragma unroll
    for (int r = 0; r < RS_ROWS; ++r) {
        const float xg = a00 * xs[r] + a01 * ysv[r] + a02;
        const float yg = a10 * xs[r] + a11 * ysv[r] + a12;
        const float wg = a20 * xs[r] + a21 * ysv[r] + a22;

        g_lds[r][w * 3 + 0] = xg;
        g_lds[r][w * 3 + 1] = yg;
        g_lds[r][w * 3 + 2] = wg;

        const int ix = (int)floorf(xg);
        const int iy = (int)floorf(yg);
        const int cx0 = min(max(ix,     0), WW - 1);
        const int cx1 = min(max(ix + 1, 0), WW - 1);
        const int cy0 = min(max(iy,     0), HH - 1);
        const int cy1 = min(max(iy + 1, 0), HH - 1);
        const float x0f = (float)cx0, x1f = (float)cx1;
        const float y0f = (float)cy0, y1f = (float)cy1;
        wgt[r * 4 + 0] = (x1f - xg) * (y1f - yg);   // wa
        wgt[r * 4 + 1] = (x1f - xg) * (yg - y0f);   // wb
        wgt[r * 4 + 2] = (xg - x0f) * (y1f - yg);   // wc
        wgt[r * 4 + 3] = (xg - x0f) * (yg - y0f);   // wd
        bo[r * 4 + 0] = base_b + (cy0 * WW + cx0) * (int)sizeof(float4);
        bo[r * 4 + 1] = base_b + (cy1 * WW + cx0) * (int)sizeof(float4);
        bo[r * 4 + 2] = base_b + (cy0 * WW + cx1) * (int)sizeof(float4);
        bo[r * 4 + 3] = base_b + (cy1 * WW + cx1) * (int)sizeof(float4);
    }

    // ---- phase 2: ALL 16 gathers in one asm block; vmcnt(0) sees ONLY them.
    //      saddr form: global_load_dwordx4 vdst, voffset(32b), s[base:base+1]
    f32x4 I0, I1, I2, I3, I4, I5, I6, I7, I8, I9, I10, I11, I12, I13, I14, I15;
    asm volatile(
        "global_load_dwordx4 %[d0],  %[a0],  %[sb]\n\t"
        "global_load_dwordx4 %[d1],  %[a1],  %[sb]\n\t"
        "global_load_dwordx4 %[d2],  %[a2],  %[sb]\n\t"
        "global_load_dwordx4 %[d3],  %[a3],  %[sb]\n\t"
        "global_load_dwordx4 %[d4],  %[a4],  %[sb]\n\t"
        "global_load_dwordx4 %[d5],  %[a5],  %[sb]\n\t"
        "global_load_dwordx4 %[d6],  %[a6],  %[sb]\n\t"
        "global_load_dwordx4 %[d7],  %[a7],  %[sb]\n\t"
        "global_load_dwordx4 %[d8],  %[a8],  %[sb]\n\t"
        "global_load_dwordx4 %[d9],  %[a9],  %[sb]\n\t"
        "global_load_dwordx4 %[d10], %[a10], %[sb]\n\t"
        "global_load_dwordx4 %[d11], %[a11], %[sb]\n\t"
        "global_load_dwordx4 %[d12], %[a12], %[sb]\n\t"
        "global_load_dwordx4 %[d13], %[a13], %[sb]\n\t"
        "global_load_dwordx4 %[d14], %[a14], %[sb]\n\t"
        "global_load_dwordx4 %[d15], %[a15], %[sb]\n\t"
        "s_waitcnt vmcnt(0)"
        : [d0]"=&v"(I0),  [d1]"=&v"(I1),  [d2]"=&v"(I2),  [d3]"=&v"(I3),
          [d4]"=&v"(I4),  [d5]"=&v"(I5),  [d6]"=&v"(I6),  [d7]"=&v"(I7),
          [d8]"=&v"(I8),  [d9]"=&v"(I9),  [d10]"=&v"(I10), [d11]"=&v"(I11),
          [d12]"=&v"(I12), [d13]"=&v"(I13), [d14]"=&v"(I14), [d15]"=&v"(I15)
        : [a0]"v"(bo[0]),  [a1]"v"(bo[1]),  [a2]"v"(bo[2]),  [a3]"v"(bo[3]),
          [a4]"v"(bo[4]),  [a5]"v"(bo[5]),  [a6]"v"(bo[6]),  [a7]"v"(bo[7]),
          [a8]"v"(bo[8]),  [a9]"v"(bo[9]),  [a10]"v"(bo[10]), [a11]"v"(bo[11]),
          [a12]"v"(bo[12]), [a13]"v"(bo[13]), [a14]"v"(bo[14]), [a15]"v"(bo[15]),
          [sb]"s"(im4)
        : "memory");

    // ---- phase 3: blend + out stores
#define BLEND_ROW(r, A, B, C, D)                                              \
    {                                                                         \
        const size_t pix = rowbase0 + (size_t)(r) * WW;                       \
        f32x4 o;                                                              \
        o.x = wgt[(r)*4+0]*A.x + wgt[(r)*4+1]*B.x + wgt[(r)*4+2]*C.x +        \
              wgt[(r)*4+3]*D.x;                                               \
        o.y = wgt[(r)*4+0]*A.y + wgt[(r)*4+1]*B.y + wgt[(r)*4+2]*C.y +        \
              wgt[(r)*4+3]*D.y;                                               \
        o.z = wgt[(r)*4+0]*A.z + wgt[(r)*4+1]*B.z + wgt[(r)*4+2]*C.z +        \
              wgt[(r)*4+3]*D.z;                                               \
        o.w = wgt[(r)*4+0]*A.w + wgt[(r)*4+1]*B.w + wgt[(r)*4+2]*C.w +        \
              wgt[(r)*4+3]*D.w;                                               \
        __builtin_nontemporal_store(o, &out4[pix]);                           \
    }
    BLEND_ROW(0, I0,  I1,  I2,  I3)
    BLEND_ROW(1, I4,  I5,  I6,  I7)
    BLEND_ROW(2, I8,  I9,  I10, I11)
    BLEND_ROW(3, I12, I13, I14, I15)
#undef BLEND_ROW

    // ---- phase 4: dump staged grid3 as contiguous float4 NT stores.
    //      Row r of grid3 = 1536 contiguous floats = 384 float4s.
    __syncthreads();
#pragma unroll
    for (int r = 0; r < RS_ROWS; ++r) {
        if (w < 384) {
            const size_t rowpix = imgbase + (size_t)(h0 + r) * WW;  // row start
            f32x4* dst = (f32x4*)(grid3 + rowpix * 3);
            const f32x4 v = *(const f32x4*)&g_lds[r][w * 4];
            __builtin_nontemporal_store(v, &dst[w]);
        }
    }
}

extern "C" void kernel_launch(void* const* d_in, const int* in_sizes, int n_in,
                              void* d_out, int out_size, void* d_ws, size_t ws_size,
                              hipStream_t stream) {
    const float* im      = (const float*)d_in[0];
    const float* defgrad = (const float*)d_in[1];
    const float* affine  = (const float*)d_in[2];

    float* out   = (float*)d_out;
    float* grid3 = out + (size_t)BB * HH * WW * CC;

    const size_t plane_elems = (size_t)BB * HH * WW;
    const size_t plane_bytes = plane_elems * sizeof(float);

    float* ysp;
    int    ys_stride;
    float* dgxp = nullptr;
    if (ws_size >= 2 * plane_bytes) {      // planar ys + planar dgx (preferred)
        ysp = (float*)d_ws;
        ys_stride = 1;
        dgxp = (float*)d_ws + plane_elems;
    } else if (ws_size >= plane_bytes) {   // planar ys only
        ysp = (float*)d_ws;
        ys_stride = 1;
    } else {                               // stash in grid3[...,1] slot (race-free)
        ysp = grid3 + 1;
        ys_stride = 3;
    }

    colscan_kernel<<<BB * (WW / CS_COLS), CS_THREADS, 0, stream>>>(
        (const f32x2*)defgrad, ysp, ys_stride, dgxp);

    rowscan_sample_kernel<<<BB * (HH / RS_ROWS), 512, 0, stream>>>(
        (const float4*)im, (const float2*)defgrad, affine,
        ysp, ys_stride, dgxp, (f32x4*)out, grid3);
}

// Round 7
// 245.721 us; speedup vs baseline: 1.0209x; 1.0209x over previous
//
#include <hip/hip_runtime.h>
#include <math.h>

#define BB 16
#define HH 512
#define WW 512
#define CC 4

typedef float f32x2 __attribute__((ext_vector_type(2)));
typedef float f32x4 __attribute__((ext_vector_type(4)));

// ---------------------------------------------------------------------------
// Kernel 1: column scan of logistic(defgrad.y); emits a MERGED float2 plane
// ws[pix] = (logistic(defgrad.x), y_scan) when workspace permits (rowscan
// then does ONE 8B load per pixel instead of two scalar loads), else falls
// back to a planar/strided ys-only plane.
//   grid: BB * (WW/32) = 256 blocks; block: 1024 threads = 32 segs x 32 cols.
// ---------------------------------------------------------------------------
#define CS_COLS    32
#define CS_THREADS 1024
#define CS_SEGS    (CS_THREADS / CS_COLS)   // 32
#define CS_CHUNK   128
#define CS_SEGH    (CS_CHUNK / CS_SEGS)     // 4
#define CS_NCHUNK  (HH / CS_CHUNK)          // 4

__global__ __launch_bounds__(CS_THREADS)
void colscan_kernel(const f32x2* __restrict__ defgrad,
                    f32x2* __restrict__ ws,            // merged (dgx, ys) plane
                    float* __restrict__ ys, int ys_stride) {  // fallback
    const int wt  = blockIdx.x % (WW / CS_COLS);
    const int b   = blockIdx.x / (WW / CS_COLS);
    const int tid = threadIdx.x;
    const int col = tid & (CS_COLS - 1);
    const int seg = tid >> 5;               // 0..31 (row base in load phase)

    __shared__ float ldsy[CS_CHUNK][CS_COLS + 1];
    __shared__ float ldsx[CS_CHUNK][CS_COLS + 1];
    __shared__ float part[CS_SEGS][CS_COLS];
    __shared__ float carry[2][CS_COLS];

    if (tid < CS_COLS) carry[0][tid] = 0.f;

    const size_t ibase = (size_t)b * HH * WW + wt * CS_COLS;  // + row*WW + col

    for (int c = 0; c < CS_NCHUNK; ++c) {
        // ---- load float2, logistic both channels, stage both in LDS
#pragma unroll
        for (int k = 0; k < 4; ++k) {
            const int r    = seg + k * 32;            // 0..127
            const int grow = c * CS_CHUNK + r;
            const size_t gi = ibase + (size_t)grow * WW + col;
            f32x2 v = __builtin_nontemporal_load(&defgrad[gi]);
            ldsx[r][col] = 2.0f / (1.0f + expf(-v.x));
            ldsy[r][col] = 2.0f / (1.0f + expf(-v.y));
        }
        __syncthreads();

        // ---- per-segment serial sums (kept in regs)
        float vals[CS_SEGH];
        float s = 0.f;
#pragma unroll
        for (int i = 0; i < CS_SEGH; ++i) {
            vals[i] = ldsy[seg * CS_SEGH + i][col];
            s += vals[i];
        }
        part[seg][col] = s;
        const float cold = carry[c & 1][col];
        __syncthreads();

        // ---- exclusive segment prefix + chunk total (broadcast reads)
        float run = cold, tot = cold;
#pragma unroll
        for (int j = 0; j < CS_SEGS; ++j) {
            float v = part[j][col];
            tot += v;
            if (j < seg) run += v;
        }
        if (seg == 0) carry[(c + 1) & 1][col] = tot;

        // ---- write scan values: merged float2 (8B/lane, coalesced) or fallback
        const size_t gidx0 =
            (size_t)(b * HH + c * CS_CHUNK + seg * CS_SEGH) * WW + wt * CS_COLS + col;
        if (ws) {
#pragma unroll
            for (int i = 0; i < CS_SEGH; ++i) {
                run += vals[i];
                f32x2 o; o.x = ldsx[seg * CS_SEGH + i][col]; o.y = run;
                __builtin_nontemporal_store(o, &ws[gidx0 + (size_t)i * WW]);
            }
        } else {
#pragma unroll
            for (int i = 0; i < CS_SEGH; ++i) {
                run += vals[i];
                __builtin_nontemporal_store(
                    run, &ys[(gidx0 + (size_t)i * WW) * (size_t)ys_stride]);
            }
        }
        __syncthreads();
    }
}

// ---------------------------------------------------------------------------
// Kernel 2: per-row fused — x_s row scan + residual affine + bilinear sample.
// v7: sector-request reduction.
//   * prologue: ONE float2 load per row (merged ws plane) instead of two
//     scalar loads (halves prologue wave-loads + exposures).
//   * gather asm reordered A,C,B,D per row: A/C share a 64B sector ~75% of
//     the time (same row, x0/x0+1); issuing them adjacently lets the second
//     lookup merge into the first's in-flight L2 request (MSHR merge).  The
//     old A,B,C,D order alternated rows y0/y1/y0/y1 — zero merge windows.
//     (yg jitters +-10..30 rows per lane because ys is a per-column random
//     walk -> each gather instr spans ~40-64 row-scattered sectors; L2
//     lookup throughput on those is the measured ~90us invariant.)
//   grid: BB*HH/4 = 2048 blocks; block: 512 threads (one per column).
// ---------------------------------------------------------------------------
#define RS_ROWS 4

__global__ __launch_bounds__(512, 4)
void rowscan_sample_kernel(const float4* __restrict__ im4,
                           const float2* __restrict__ defgrad,
                           const float*  __restrict__ affine,
                           const f32x2*  __restrict__ wsp,   // merged plane
                           const float*  __restrict__ ys, int ys_stride,
                           f32x4* __restrict__ out4,
                           float*  __restrict__ grid3) {
    // bijective XCD swizzle: 2048 % 8 == 0, consecutive logical ids per XCD
    const int nwg = BB * (HH / RS_ROWS);
    const int cpx = nwg / 8;
    const int l   = (blockIdx.x & 7) * cpx + (blockIdx.x >> 3);
    const int hb  = l % (HH / RS_ROWS);
    const int b   = l / (HH / RS_ROWS);
    const int h0  = hb * RS_ROWS;

    const int w    = threadIdx.x;          // 0..511 column
    const int lane = w & 63;
    const int wv   = w >> 6;               // 0..7

    const size_t imgbase  = (size_t)b * HH * WW;
    const size_t rowbase0 = imgbase + (size_t)h0 * WW + w;

    __shared__ __align__(16) float g_lds[RS_ROWS][WW * 3];  // staged grid3 rows
    __shared__ float wsum[8][RS_ROWS];

    // ---- early independent loads: (dgx, ys) merged, or fallback path
    float dgxv[RS_ROWS], ysv[RS_ROWS];
    if (wsp) {
#pragma unroll
        for (int r = 0; r < RS_ROWS; ++r) {
            const f32x2 v = wsp[rowbase0 + (size_t)r * WW];
            dgxv[r] = v.x;
            ysv[r]  = v.y;
        }
    } else {
#pragma unroll
        for (int r = 0; r < RS_ROWS; ++r) {
            const size_t pix = rowbase0 + (size_t)r * WW;
            dgxv[r] = defgrad[pix].x;
            ysv[r]  = ys[pix * (size_t)ys_stride];
        }
#pragma unroll
        for (int r = 0; r < RS_ROWS; ++r)
            dgxv[r] = 2.0f / (1.0f + expf(-dgxv[r]));
    }

    // ---- 4 simultaneous inclusive block scans (wave scan + LDS combine)
    float x0 = dgxv[0], x1 = dgxv[1], x2 = dgxv[2], x3 = dgxv[3];
#pragma unroll
    for (int off = 1; off < 64; off <<= 1) {
        float n0 = __shfl_up(x0, off, 64);
        float n1 = __shfl_up(x1, off, 64);
        float n2 = __shfl_up(x2, off, 64);
        float n3 = __shfl_up(x3, off, 64);
        if (lane >= off) { x0 += n0; x1 += n1; x2 += n2; x3 += n3; }
    }
    if (lane == 63) {
        wsum[wv][0] = x0; wsum[wv][1] = x1; wsum[wv][2] = x2; wsum[wv][3] = x3;
    }
    __syncthreads();
    float p0 = 0.f, p1 = 0.f, p2 = 0.f, p3 = 0.f;
    for (int j = 0; j < wv; ++j) {
        p0 += wsum[j][0]; p1 += wsum[j][1]; p2 += wsum[j][2]; p3 += wsum[j][3];
    }
    const float xs[RS_ROWS] = { x0 + p0, x1 + p1, x2 + p2, x3 + p3 };

    // ---- residual affine (A = affine + I), uniform per block -> SGPRs
    const float* Ab = affine + b * 9;
    const float a00 = Ab[0] + 1.f, a01 = Ab[1], a02 = Ab[2];
    const float a10 = Ab[3], a11 = Ab[4] + 1.f, a12 = Ab[5];
    const float a20 = Ab[6], a21 = Ab[7], a22 = Ab[8] + 1.f;

    // ---- phase 1: addresses + weights; grid3 -> LDS (no global stores here)
    int   bo [4 * RS_ROWS];                // byte voffsets (fit in 31 bits)
    float wgt[4 * RS_ROWS];
    const int base_b = (int)(imgbase * sizeof(float4));
#pragma unroll
    for (int r = 0; r < RS_ROWS; ++r) {
        const float xg = a00 * xs[r] + a01 * ysv[r] + a02;
        const float yg = a10 * xs[r] + a11 * ysv[r] + a12;
        const float wg = a20 * xs[r] + a21 * ysv[r] + a22;

        g_lds[r][w * 3 + 0] = xg;
        g_lds[r][w * 3 + 1] = yg;
        g_lds[r][w * 3 + 2] = wg;

        const int ix = (int)floorf(xg);
        const int iy = (int)floorf(yg);
        const int cx0 = min(max(ix,     0), WW - 1);
        const int cx1 = min(max(ix + 1, 0), WW - 1);
        const int cy0 = min(max(iy,     0), HH - 1);
        const int cy1 = min(max(iy + 1, 0), HH - 1);
        const float x0f = (float)cx0, x1f = (float)cx1;
        const float y0f = (float)cy0, y1f = (float)cy1;
        wgt[r * 4 + 0] = (x1f - xg) * (y1f - yg);   // wa -> Ia (y0,x0)
        wgt[r * 4 + 1] = (x1f - xg) * (yg - y0f);   // wb -> Ib (y1,x0)
        wgt[r * 4 + 2] = (xg - x0f) * (y1f - yg);   // wc -> Ic (y0,x1)
        wgt[r * 4 + 3] = (xg - x0f) * (yg - y0f);   // wd -> Id (y1,x1)
        bo[r * 4 + 0] = base_b + (cy0 * WW + cx0) * (int)sizeof(float4);
        bo[r * 4 + 1] = base_b + (cy1 * WW + cx0) * (int)sizeof(float4);
        bo[r * 4 + 2] = base_b + (cy0 * WW + cx1) * (int)sizeof(float4);
        bo[r * 4 + 3] = base_b + (cy1 * WW + cx1) * (int)sizeof(float4);
    }

    // ---- phase 2: ALL 16 gathers, ordered A,C (row y0) then B,D (row y1)
    //      per r so same-sector pairs are temporally adjacent (MSHR merge).
    //      saddr form: global_load_dwordx4 vdst, voffset(32b), s[base:base+1]
    f32x4 I0, I1, I2, I3, I4, I5, I6, I7, I8, I9, I10, I11, I12, I13, I14, I15;
    asm volatile(
        "global_load_dwordx4 %[d0],  %[a0],  %[sb]\n\t"   // r0 A (y0,x0)
        "global_load_dwordx4 %[d2],  %[a2],  %[sb]\n\t"   // r0 C (y0,x1)
        "global_load_dwordx4 %[d1],  %[a1],  %[sb]\n\t"   // r0 B (y1,x0)
        "global_load_dwordx4 %[d3],  %[a3],  %[sb]\n\t"   // r0 D (y1,x1)
        "global_load_dwordx4 %[d4],  %[a4],  %[sb]\n\t"   // r1 A
        "global_load_dwordx4 %[d6],  %[a6],  %[sb]\n\t"   // r1 C
        "global_load_dwordx4 %[d5],  %[a5],  %[sb]\n\t"   // r1 B
        "global_load_dwordx4 %[d7],  %[a7],  %[sb]\n\t"   // r1 D
        "global_load_dwordx4 %[d8],  %[a8],  %[sb]\n\t"   // r2 A
        "global_load_dwordx4 %[d10], %[a10], %[sb]\n\t"   // r2 C
        "global_load_dwordx4 %[d9],  %[a9],  %[sb]\n\t"   // r2 B
        "global_load_dwordx4 %[d11], %[a11], %[sb]\n\t"   // r2 D
        "global_load_dwordx4 %[d12], %[a12], %[sb]\n\t"   // r3 A
        "global_load_dwordx4 %[d14], %[a14], %[sb]\n\t"   // r3 C
        "global_load_dwordx4 %[d13], %[a13], %[sb]\n\t"   // r3 B
        "global_load_dwordx4 %[d15], %[a15], %[sb]\n\t"   // r3 D
        "s_waitcnt vmcnt(0)"
        : [d0]"=&v"(I0),  [d1]"=&v"(I1),  [d2]"=&v"(I2),  [d3]"=&v"(I3),
          [d4]"=&v"(I4),  [d5]"=&v"(I5),  [d6]"=&v"(I6),  [d7]"=&v"(I7),
          [d8]"=&v"(I8),  [d9]"=&v"(I9),  [d10]"=&v"(I10), [d11]"=&v"(I11),
          [d12]"=&v"(I12), [d13]"=&v"(I13), [d14]"=&v"(I14), [d15]"=&v"(I15)
        : [a0]"v"(bo[0]),  [a1]"v"(bo[1]),  [a2]"v"(bo[2]),  [a3]"v"(bo[3]),
          [a4]"v"(bo[4]),  [a5]"v"(bo[5]),  [a6]"v"(bo[6]),  [a7]"v"(bo[7]),
          [a8]"v"(bo[8]),  [a9]"v"(bo[9]),  [a10]"v"(bo[10]), [a11]"v"(bo[11]),
          [a12]"v"(bo[12]), [a13]"v"(bo[13]), [a14]"v"(bo[14]), [a15]"v"(bo[15]),
          [sb]"s"(im4)
        : "memory");

    // ---- phase 3: blend + out stores
#define BLEND_ROW(r, A, B, C, D)                                              \
    {                                                                         \
        const size_t pix = rowbase0 + (size_t)(r) * WW;                       \
        f32x4 o;                                                              \
        o.x = wgt[(r)*4+0]*A.x + wgt[(r)*4+1]*B.x + wgt[(r)*4+2]*C.x +        \
              wgt[(r)*4+3]*D.x;                                               \
        o.y = wgt[(r)*4+0]*A.y + wgt[(r)*4+1]*B.y + wgt[(r)*4+2]*C.y +        \
              wgt[(r)*4+3]*D.y;                                               \
        o.z = wgt[(r)*4+0]*A.z + wgt[(r)*4+1]*B.z + wgt[(r)*4+2]*C.z +        \
              wgt[(r)*4+3]*D.z;                                               \
        o.w = wgt[(r)*4+0]*A.w + wgt[(r)*4+1]*B.w + wgt[(r)*4+2]*C.w +        \
              wgt[(r)*4+3]*D.w;                                               \
        __builtin_nontemporal_store(o, &out4[pix]);                           \
    }
    BLEND_ROW(0, I0,  I1,  I2,  I3)
    BLEND_ROW(1, I4,  I5,  I6,  I7)
    BLEND_ROW(2, I8,  I9,  I10, I11)
    BLEND_ROW(3, I12, I13, I14, I15)
#undef BLEND_ROW

    // ---- phase 4: dump staged grid3 as contiguous float4 NT stores.
    __syncthreads();
#pragma unroll
    for (int r = 0; r < RS_ROWS; ++r) {
        if (w < 384) {
            const size_t rowpix = imgbase + (size_t)(h0 + r) * WW;  // row start
            f32x4* dst = (f32x4*)(grid3 + rowpix * 3);
            const f32x4 v = *(const f32x4*)&g_lds[r][w * 4];
            __builtin_nontemporal_store(v, &dst[w]);
        }
    }
}

extern "C" void kernel_launch(void* const* d_in, const int* in_sizes, int n_in,
                              void* d_out, int out_size, void* d_ws, size_t ws_size,
                              hipStream_t stream) {
    const float* im      = (const float*)d_in[0];
    const float* defgrad = (const float*)d_in[1];
    const float* affine  = (const float*)d_in[2];

    float* out   = (float*)d_out;
    float* grid3 = out + (size_t)BB * HH * WW * CC;

    const size_t plane_elems = (size_t)BB * HH * WW;
    const size_t plane_bytes = plane_elems * sizeof(float);

    f32x2* wsp = nullptr;
    float* ysp = nullptr;
    int    ys_stride = 1;
    if (ws_size >= 2 * plane_bytes) {      // merged (dgx, ys) float2 plane
        wsp = (f32x2*)d_ws;
    } else if (ws_size >= plane_bytes) {   // planar ys only
        ysp = (float*)d_ws;
        ys_stride = 1;
    } else {                               // stash in grid3[...,1] slot (race-free)
        ysp = grid3 + 1;
        ys_stride = 3;
    }

    colscan_kernel<<<BB * (WW / CS_COLS), CS_THREADS, 0, stream>>>(
        (const f32x2*)defgrad, wsp, ysp, ys_stride);

    rowscan_sample_kernel<<<BB * (HH / RS_ROWS), 512, 0, stream>>>(
        (const float4*)im, (const float2*)defgrad, affine,
        wsp, ysp, ys_stride, (f32x4*)out, grid3);
}